// Round 3
// baseline (2456.631 us; speedup 1.0000x reference)
//
#include <hip/hip_runtime.h>

// APPNP: h0 = relu(x@W1+b1)@W2+b2 ; 10x: h = 0.9*(D^-1/2 A_sl D^-1/2 h) + 0.1*h0
// R2 build: bucket-binned CSR (64 dst/bucket), LDS per-bucket build.
// R3(mlp, kept): W1/W2 pre-packed in MFMA frag order (global->VGPR B), x staged in
//   LDS dbuf, h1s XOR-swizzled. 121us verified.  [R4's global-A variant regressed
//   3.5x: per-lane 2KB-stride latency chase; reverted.]
// R5 (this round) prop locality:
//   - buildcsr counting-sort key extended to (local_dst, src>>12): each node's
//     edges grouped into 32 ascending 4096-node src ranges (512KB of hs each).
//     Emits cnt16[N][32] (u16 per-range counts) alongside rp.
//   - prop: single co-resident cohort (782 blocks), each wave owns 32 nodes
//     (8 slots x G=4), sweeps ranges in lockstep chip-wide -> gathers hit a
//     moving 512KB L2-resident window. Same 16B/lane gather txns as before.

typedef unsigned short u16;
typedef unsigned int   u32;
typedef __bf16    bfx8  __attribute__((ext_vector_type(8)));
typedef _Float16  h16x8 __attribute__((ext_vector_type(8)));
typedef float     f32x4 __attribute__((ext_vector_type(4)));

#define CAP 4096      // per-bucket edge capacity (mean 2048, sigma 45)
#define EPB 16384     // edges per binscat block
#define NBMAX 1792    // bucket count upper bound for LDS arrays (N<=114k)

__device__ __forceinline__ u16 f2bf(float f) {
    u32 u = __float_as_uint(f);
    u += 0x7fffu + ((u >> 16) & 1u);   // RNE
    return (u16)(u >> 16);
}

// ---------------- build pass 1: bin edges by dst bucket ----------------

__global__ __launch_bounds__(256) void binscat_kernel(
        const int* __restrict__ src, const int* __restrict__ dst,
        int* __restrict__ gcur, u32* __restrict__ binned, int E, int NB) {
    __shared__ int cnt[NBMAX];
    int tid = threadIdx.x;
#pragma unroll
    for (int j = 0; j < NBMAX / 256; ++j) cnt[tid + j * 256] = 0;
    __syncthreads();
    int e0 = blockIdx.x * EPB;
    for (int r = 0; r < EPB / 256; ++r) {
        int i = e0 + r * 256 + tid;
        if (i < E) atomicAdd(&cnt[dst[i] >> 6], 1);
    }
    __syncthreads();
    for (int j = 0; j < NBMAX / 256; ++j) {
        int b = tid + j * 256;
        if (b < NB) {
            int c = cnt[b];
            cnt[b] = (c > 0) ? atomicAdd(&gcur[b], c) : 0;
        }
    }
    __syncthreads();
    for (int r = 0; r < EPB / 256; ++r) {
        int i = e0 + r * 256 + tid;
        if (i < E) {
            int d = dst[i];
            int s = src[i];
            int bb = d >> 6;
            int p = atomicAdd(&cnt[bb], 1);
            if (p < CAP) binned[(size_t)bb * CAP + p] = ((u32)(d & 63) << 17) | (u32)s;
        }
    }
}

// ---------------- build pass 2: exclusive scan of bucket counts ----------------

__global__ __launch_bounds__(256) void bucket_scan_kernel(
        const int* __restrict__ gcur, int* __restrict__ bbase,
        int* __restrict__ rp, int N, int NB) {
    __shared__ int tsum[256];
    int tid = threadIdx.x;
    int loc[7];
    int run = 0;
#pragma unroll
    for (int j = 0; j < 7; ++j) {
        int b = tid * 7 + j;
        int v = 0;
        if (b < NB) { v = gcur[b]; if (v > CAP) v = CAP; }
        loc[j] = run;
        run += v;
    }
    tsum[tid] = run;
    __syncthreads();
    for (int off = 1; off < 256; off <<= 1) {
        int t = (tid >= off) ? tsum[tid - off] : 0;
        __syncthreads();
        tsum[tid] += t;
        __syncthreads();
    }
    int texcl = tsum[tid] - run;
#pragma unroll
    for (int j = 0; j < 7; ++j) {
        int b = tid * 7 + j;
        if (b < NB) bbase[b] = texcl + loc[j];
    }
    if (tid == 255) rp[N] = tsum[255];   // == E
}

// ---------------- build pass 3: per-bucket (dst,src-range) CSR in LDS ----------------
// key = local_dst*32 + (src>>12): counting sort gives, per node, edges grouped
// into 32 ascending src ranges. Emits rp[node] (segment start), dinv, and
// cnt16[node][32] per-range counts.

__global__ __launch_bounds__(256) void buildcsr_kernel(
        const u32* __restrict__ binned, const int* __restrict__ gcur,
        const int* __restrict__ bbase, int* __restrict__ rp,
        u16* __restrict__ cnt16, float* __restrict__ dinv,
        int* __restrict__ csr, int N) {
    __shared__ u32 eb[CAP];        // 16 KB staged packed edges
    __shared__ int lcsr[CAP];      // 16 KB bucket-local csr
    __shared__ int cnt2[2048];     // 8 KB (local_dst*32 + srchi)
    __shared__ int cur2[2048];     // 8 KB cursors / scan
    __shared__ int tsum[256];
    int b = blockIdx.x;
    int tid = threadIdx.x;
    int cntB = gcur[b]; if (cntB > CAP) cntB = CAP;
    int base = bbase[b];
#pragma unroll
    for (int j = 0; j < 8; ++j) cnt2[tid * 8 + j] = 0;
    __syncthreads();
    for (int idx = tid; idx < cntB; idx += 256) {
        u32 v = binned[(size_t)b * CAP + idx];
        eb[idx] = v;
        int key = (int)(((v >> 17) << 5) | ((v & 0x1FFFFu) >> 12));
        atomicAdd(&cnt2[key], 1);
    }
    __syncthreads();
    // hierarchical exclusive scan of cnt2[0..2048)
    int loc[8];
    int run = 0;
#pragma unroll
    for (int j = 0; j < 8; ++j) { loc[j] = run; run += cnt2[tid * 8 + j]; }
    tsum[tid] = run;
    __syncthreads();
    for (int off = 1; off < 256; off <<= 1) {
        int t = (tid >= off) ? tsum[tid - off] : 0;
        __syncthreads();
        tsum[tid] += t;
        __syncthreads();
    }
    int texcl = tsum[tid] - run;
#pragma unroll
    for (int j = 0; j < 8; ++j) cur2[tid * 8 + j] = texcl + loc[j];
    // per-range counts out (8 u16 per thread, coalesced 16B stores)
    {
        u16 pk[8];
#pragma unroll
        for (int j = 0; j < 8; ++j) pk[j] = (u16)cnt2[tid * 8 + j];
        *(uint4*)&cnt16[(size_t)b * 2048 + tid * 8] = *(uint4*)pk;
    }
    __syncthreads();
    if (tid < 64) {
        int node = b * 64 + tid;
        int lo = cur2[tid * 32];
        int hi = (tid == 63) ? cntB : cur2[(tid + 1) * 32];
        if (node < N) {
            rp[node] = base + lo;
            dinv[node] = rsqrtf(1.0f + (float)(hi - lo));   // +1 self-loop
        }
    }
    __syncthreads();
    for (int idx = tid; idx < cntB; idx += 256) {
        u32 v = eb[idx];
        int key = (int)(((v >> 17) << 5) | ((v & 0x1FFFFu) >> 12));
        int p = atomicAdd(&cur2[key], 1);
        lcsr[p] = (int)(v & 0x1FFFFu);
    }
    __syncthreads();
    for (int idx = tid; idx < cntB; idx += 256)
        csr[base + idx] = lcsr[idx];   // fully coalesced
}

// ---------------- weight pre-pack to MFMA fragment order (bf16) ----------------

__global__ void prepw1_kernel(const float* __restrict__ W1, u16* __restrict__ W1f) {
    int f = blockIdx.x * 256 + threadIdx.x;   // 16384 frags
    int lane = f & 63;
    int nt = (f >> 6) & 3;
    int w  = (f >> 8) & 3;
    int t  = f >> 10;
    int col = w * 64 + nt * 16 + (lane & 15);
    int k0  = t * 32 + ((lane >> 4) << 3);
    u32 pk[4];
#pragma unroll
    for (int j = 0; j < 4; ++j) {
        u16 lo = f2bf(W1[(size_t)(k0 + 2 * j) * 256 + col]);
        u16 hi = f2bf(W1[(size_t)(k0 + 2 * j + 1) * 256 + col]);
        pk[j] = (u32)lo | ((u32)hi << 16);
    }
    *(uint4*)&W1f[(size_t)f * 8] = make_uint4(pk[0], pk[1], pk[2], pk[3]);
}

__global__ void prepw2_kernel(const float* __restrict__ W2, u16* __restrict__ W2f) {
    int f = blockIdx.x * 256 + threadIdx.x;   // 2048 frags
    int lane = f & 63;
    int nt = (f >> 6) & 3;
    int t  = f >> 8;
    int col = nt * 16 + (lane & 15);
    int k0  = t * 32 + ((lane >> 4) << 3);
    u32 pk[4];
#pragma unroll
    for (int j = 0; j < 4; ++j) {
        u16 lo = f2bf(W2[(size_t)(k0 + 2 * j) * 64 + col]);
        u16 hi = f2bf(W2[(size_t)(k0 + 2 * j + 1) * 64 + col]);
        pk[j] = (u32)lo | ((u32)hi << 16);
    }
    *(uint4*)&W2f[(size_t)f * 8] = make_uint4(pk[0], pk[1], pk[2], pk[3]);
}

// ---------------- fused MLP -> h0 (fp32) and hs = dinv*h0 (fp16) ----------------
// (R1-verified structure: x staged in LDS dbuf, B-frags global, h1s swizzled.)

__global__ __launch_bounds__(256) void mlp_kernel(
        const float* __restrict__ x, const u16* __restrict__ W1f,
        const float* __restrict__ b1, const u16* __restrict__ W2f,
        const float* __restrict__ b2, const float* __restrict__ dinv,
        float* __restrict__ h0, _Float16* __restrict__ hA, int N) {
    __shared__ char lds[32768];
    u16* xs  = (u16*)lds;              // phase1: [2][64][40] u16 dbuf (10240 B)
    u16* h1s = (u16*)lds;              // phase2: [64][256] u16 swizzled (32768 B)

    const int tid  = threadIdx.x;
    const int wave = tid >> 6;
    const int lane = tid & 63;
    const int lq   = lane >> 4;
    const int lr   = lane & 15;
    const int blockRow = blockIdx.x * 64;

    const int sr = tid >> 2;
    const int sc = (tid & 3) << 3;
    const int gr = blockRow + sr;
    const bool haveRow = (gr < N);
    const float* xp = x + (size_t)(haveRow ? gr : 0) * 512 + sc;

    f32x4 acc[4][4];
#pragma unroll
    for (int a = 0; a < 4; ++a)
#pragma unroll
        for (int b = 0; b < 4; ++b) acc[a][b] = (f32x4){0.f, 0.f, 0.f, 0.f};

    // prologue: stage x tile 0 into buf 0
    {
        float v[8];
#pragma unroll
        for (int j = 0; j < 8; ++j) v[j] = 0.f;
        if (haveRow) {
            float4 u0 = *(const float4*)(xp);
            float4 u1 = *(const float4*)(xp + 4);
            v[0]=u0.x; v[1]=u0.y; v[2]=u0.z; v[3]=u0.w;
            v[4]=u1.x; v[5]=u1.y; v[6]=u1.z; v[7]=u1.w;
        }
        u32 pk[4];
#pragma unroll
        for (int j = 0; j < 4; ++j)
            pk[j] = (u32)f2bf(v[2*j]) | ((u32)f2bf(v[2*j+1]) << 16);
        *(uint4*)&xs[sr * 40 + sc] = make_uint4(pk[0], pk[1], pk[2], pk[3]);
    }

    const bfx8* w1q = (const bfx8*)W1f;

    // ---- GEMM1: K=512 in 16 steps of 32 ----
    for (int t = 0; t < 16; ++t) {
        bfx8 fb0 = w1q[(t * 16 + wave * 4 + 0) * 64 + lane];
        bfx8 fb1 = w1q[(t * 16 + wave * 4 + 1) * 64 + lane];
        bfx8 fb2 = w1q[(t * 16 + wave * 4 + 2) * 64 + lane];
        bfx8 fb3 = w1q[(t * 16 + wave * 4 + 3) * 64 + lane];
        float v[8];
#pragma unroll
        for (int j = 0; j < 8; ++j) v[j] = 0.f;
        if (t < 15 && haveRow) {
            const float* p = xp + (t + 1) * 32;
            float4 u0 = *(const float4*)(p);
            float4 u1 = *(const float4*)(p + 4);
            v[0]=u0.x; v[1]=u0.y; v[2]=u0.z; v[3]=u0.w;
            v[4]=u1.x; v[5]=u1.y; v[6]=u1.z; v[7]=u1.w;
        }
        __syncthreads();
        const u16* cur = xs + (t & 1) * 2560;
        bfx8 fa[4];
#pragma unroll
        for (int mt = 0; mt < 4; ++mt)
            fa[mt] = *(const bfx8*)&cur[(mt * 16 + lr) * 40 + lq * 8];
#pragma unroll
        for (int mt = 0; mt < 4; ++mt) {
            acc[mt][0] = __builtin_amdgcn_mfma_f32_16x16x32_bf16(fa[mt], fb0, acc[mt][0], 0, 0, 0);
            acc[mt][1] = __builtin_amdgcn_mfma_f32_16x16x32_bf16(fa[mt], fb1, acc[mt][1], 0, 0, 0);
            acc[mt][2] = __builtin_amdgcn_mfma_f32_16x16x32_bf16(fa[mt], fb2, acc[mt][2], 0, 0, 0);
            acc[mt][3] = __builtin_amdgcn_mfma_f32_16x16x32_bf16(fa[mt], fb3, acc[mt][3], 0, 0, 0);
        }
        if (t < 15) {
            u16* nxt = xs + ((t + 1) & 1) * 2560;
            u32 pk[4];
#pragma unroll
            for (int j = 0; j < 4; ++j)
                pk[j] = (u32)f2bf(v[2*j]) | ((u32)f2bf(v[2*j+1]) << 16);
            *(uint4*)&nxt[sr * 40 + sc] = make_uint4(pk[0], pk[1], pk[2], pk[3]);
        }
    }
    __syncthreads();   // all fa reads done; reuse LDS as h1s

    // ---- epilogue1: bias+relu -> h1s (bf16, swizzled col ^= (row&7)<<3) ----
#pragma unroll
    for (int nt = 0; nt < 4; ++nt) {
        int col = wave * 64 + nt * 16 + lr;
        float bb = b1[col];
#pragma unroll
        for (int mt = 0; mt < 4; ++mt)
#pragma unroll
            for (int r = 0; r < 4; ++r) {
                int row = mt * 16 + lq * 4 + r;
                float vv = acc[mt][nt][r] + bb;
                vv = vv > 0.f ? vv : 0.f;
                h1s[row * 256 + (col ^ ((row & 7) << 3))] = f2bf(vv);
            }
    }
    __syncthreads();

    // ---- GEMM2: wave w -> rows [16w,16w+16), cols 0..63, K=256 ----
    f32x4 acc2[4];
#pragma unroll
    for (int a = 0; a < 4; ++a) acc2[a] = (f32x4){0.f, 0.f, 0.f, 0.f};
    const bfx8* w2q = (const bfx8*)W2f;
    const int row2 = wave * 16 + lr;
    const int sw2  = (row2 & 7) << 3;
#pragma unroll
    for (int t2 = 0; t2 < 8; ++t2) {
        bfx8 a = *(const bfx8*)&h1s[row2 * 256 + ((t2 * 32 + lq * 8) ^ sw2)];
#pragma unroll
        for (int nt = 0; nt < 4; ++nt) {
            bfx8 b = w2q[(t2 * 4 + nt) * 64 + lane];
            acc2[nt] = __builtin_amdgcn_mfma_f32_16x16x32_bf16(a, b, acc2[nt], 0, 0, 0);
        }
    }
    // ---- epilogue2: bias, store h0 (fp32) and hs=dinv*h0 (fp16, dense) ----
#pragma unroll
    for (int nt = 0; nt < 4; ++nt) {
        int col = nt * 16 + lr;
        float bb = b2[col];
#pragma unroll
        for (int r = 0; r < 4; ++r) {
            int row = wave * 16 + lq * 4 + r;
            int g = blockRow + row;
            if (g < N) {
                float vv = acc2[nt][r] + bb;
                size_t idx = (size_t)g * 64 + col;
                h0[idx] = vv;
                hA[idx] = (_Float16)(vv * dinv[g]);
            }
        }
    }
}

// ---------------- propagation: range-major lockstep sweep ----------------
// One co-resident cohort. Wave owns 32 nodes (8 slots x G=4); lane = slot*8 + l,
// l covers cols l*8..l*8+8 (16B gathers). All waves walk src ranges 0..31 in
// lockstep -> chip-wide gather window = 512KB (L2-resident).

template <typename OUTT>
__global__ __launch_bounds__(256) void prop_kernel(
        const _Float16* __restrict__ hs, const float* __restrict__ h0,
        const float* __restrict__ dinv, const int* __restrict__ rp,
        const u16* __restrict__ cnt16, const int* __restrict__ csr,
        OUTT* __restrict__ hout, int N) {
    const int tid  = threadIdx.x;
    const int wid  = (blockIdx.x << 2) + (tid >> 6);   // global wave id
    const int lane = tid & 63;
    const int sl   = lane >> 3;        // node slot 0..7
    const int l    = lane & 7;         // col group
    const int nbase = wid * 32 + sl;

    float a[4][8];
    int e[4];
    int nodes[4];
    bool val[4];
#pragma unroll
    for (int g = 0; g < 4; ++g) {
        int i = nbase + g * 8;
        nodes[g] = i;
        val[g] = (i < N);
        int ii = val[g] ? i : 0;
        e[g] = rp[ii];
        h16x8 self = *(const h16x8*)(hs + (size_t)ii * 64 + l * 8);
#pragma unroll
        for (int j = 0; j < 8; ++j) a[g][j] = (float)self[j];   // self-loop init
    }

    for (int rb = 0; rb < 4; ++rb) {           // 4 blocks of 8 ranges
        uint4 cv[4];
#pragma unroll
        for (int g = 0; g < 4; ++g)
            cv[g] = *(const uint4*)&cnt16[(size_t)(val[g] ? nodes[g] : 0) * 32 + rb * 8];
#pragma unroll
        for (int rr = 0; rr < 8; ++rr) {
#pragma unroll
            for (int g = 0; g < 4; ++g) {
                u32 w = ((const u32*)&cv[g])[rr >> 1];
                int c = (int)((w >> ((rr & 1) << 4)) & 0xFFFFu);
                if (!val[g]) c = 0;
                int ee = e[g];
                e[g] = ee + c;
                for (int k = 0; k < c; ++k) {
                    int s0 = csr[ee + k];
                    h16x8 gv = *(const h16x8*)(hs + (size_t)s0 * 64 + l * 8);
#pragma unroll
                    for (int j = 0; j < 8; ++j) a[g][j] += (float)gv[j];
                }
            }
        }
    }

#pragma unroll
    for (int g = 0; g < 4; ++g) {
        if (!val[g]) continue;
        int i = nodes[g];
        float dv = dinv[i];
        float c1 = 0.9f * dv;
        const float* h0p = h0 + (size_t)i * 64 + l * 8;
        float o[8];
#pragma unroll
        for (int j = 0; j < 8; ++j) o[j] = fmaf(c1, a[g][j], 0.1f * h0p[j]);
        if constexpr (sizeof(OUTT) == 2) {
            h16x8 ov;
#pragma unroll
            for (int j = 0; j < 8; ++j) ov[j] = (_Float16)(dv * o[j]);   // hs_new
            *(h16x8*)((_Float16*)hout + (size_t)i * 64 + l * 8) = ov;
        } else {
            float* op = (float*)hout + (size_t)i * 64 + l * 8;
            *(float4*)op       = make_float4(o[0], o[1], o[2], o[3]);
            *(float4*)(op + 4) = make_float4(o[4], o[5], o[6], o[7]);
        }
    }
}

// ---------------- launch ----------------

extern "C" void kernel_launch(void* const* d_in, const int* in_sizes, int n_in,
                              void* d_out, int out_size, void* d_ws, size_t ws_size,
                              hipStream_t stream) {
    const float* x  = (const float*)d_in[0];
    const int*   ei = (const int*)d_in[1];
    const float* W1 = (const float*)d_in[2];
    const float* b1 = (const float*)d_in[3];
    const float* W2 = (const float*)d_in[4];
    const float* b2 = (const float*)d_in[5];
    const int N = in_sizes[0] / 512;
    const int E = in_sizes[1] / 2;
    const int NB = (N + 63) / 64;
    const int* src = ei;
    const int* dst = ei + E;

    char* w = (char*)d_ws;
    size_t off = 0;
    auto alloc = [&](size_t bytes) -> char* {
        char* p = w + off;
        off = (off + bytes + 1023) & ~(size_t)1023;
        return p;
    };
    int*      gcur  = (int*)alloc((size_t)NB * 4);
    int*      bbase = (int*)alloc((size_t)NB * 4);
    int*      rp    = (int*)alloc(((size_t)N + 1) * 4);
    float*    dinv  = (float*)alloc((size_t)N * 4);
    u16*      cnt16 = (u16*)alloc((size_t)NB * 2048 * 2);   // [node][32] range counts
    int*      csr   = (int*)alloc((size_t)E * 4);
    u32*      binned= (u32*)alloc((size_t)NB * CAP * 4);
    u16*      W1f   = (u16*)alloc(512 * 256 * 2);
    u16*      W2f   = (u16*)alloc(256 * 64 * 2);
    float*    h0    = (float*)alloc((size_t)N * 64 * 4);
    _Float16* hA    = (_Float16*)alloc((size_t)N * 64 * 2);
    _Float16* hB    = (_Float16*)alloc((size_t)N * 64 * 2);
    // ws use ~98 MB

    hipMemsetAsync(gcur, 0, (size_t)NB * 4, stream);
    binscat_kernel<<<(E + EPB - 1) / EPB, 256, 0, stream>>>(src, dst, gcur, binned, E, NB);
    bucket_scan_kernel<<<1, 256, 0, stream>>>(gcur, bbase, rp, N, NB);
    buildcsr_kernel<<<NB, 256, 0, stream>>>(binned, gcur, bbase, rp, cnt16, dinv, csr, N);
    prepw1_kernel<<<64, 256, 0, stream>>>(W1, W1f);
    prepw2_kernel<<<8, 256, 0, stream>>>(W2, W2f);
    mlp_kernel<<<(N + 63) / 64, 256, 0, stream>>>(x, W1f, b1, W2f, b2, dinv, h0, hA, N);

    const _Float16* pin = hA;
    int pgrid = (N + 127) / 128;   // 4 waves x 32 nodes per block -> one cohort
    for (int it = 0; it < 9; ++it) {
        _Float16* pout = (it & 1) ? hA : hB;
        prop_kernel<_Float16><<<pgrid, 256, 0, stream>>>(pin, h0, dinv, rp, cnt16, csr, pout, N);
        pin = pout;
    }
    prop_kernel<float><<<pgrid, 256, 0, stream>>>(pin, h0, dinv, rp, cnt16, csr, (float*)d_out, N);
}

// Round 4
// 981.647 us; speedup vs baseline: 2.5026x; 2.5026x over previous
//
#include <hip/hip_runtime.h>

// APPNP: h0 = relu(x@W1+b1)@W2+b2 ; 10x: h = 0.9*(D^-1/2 A_sl D^-1/2 h) + 0.1*h0
// R2 build: bucket-binned CSR (64 dst/bucket), LDS per-bucket build.
// R3 mlp (kept, 121us verified): W1/W2 pre-packed in MFMA frag order, x staged in
//   LDS dbuf, h1s XOR-swizzled.
// R5 build (kept): counting-sort key (local_dst, src>>12) -> each node's edge
//   list is src-ascending at 4096-node granularity. csr order IS the locality.
// R6 (this round) prop: back to the simple R1 gather loop (8 lanes/node,
//   16B/lane, no bookkeeping) running over the src-sorted csr. All in-flight
//   nodes at edge-index k read src ~ N*k/32 +- ~1MB -> L2-resident moving
//   window, for free. [R3's explicit range sweep had the locality but paid
//   2.5x divergence+bookkeeping overhead -> 205us/iter; deleted.]

typedef unsigned short u16;
typedef unsigned int   u32;
typedef __bf16    bfx8  __attribute__((ext_vector_type(8)));
typedef _Float16  h16x8 __attribute__((ext_vector_type(8)));
typedef float     f32x4 __attribute__((ext_vector_type(4)));

#define CAP 4096      // per-bucket edge capacity (mean 2048, sigma 45)
#define EPB 16384     // edges per binscat block
#define NBMAX 1792    // bucket count upper bound for LDS arrays (N<=114k)

__device__ __forceinline__ u16 f2bf(float f) {
    u32 u = __float_as_uint(f);
    u += 0x7fffu + ((u >> 16) & 1u);   // RNE
    return (u16)(u >> 16);
}

// ---------------- build pass 1: bin edges by dst bucket ----------------

__global__ __launch_bounds__(256) void binscat_kernel(
        const int* __restrict__ src, const int* __restrict__ dst,
        int* __restrict__ gcur, u32* __restrict__ binned, int E, int NB) {
    __shared__ int cnt[NBMAX];
    int tid = threadIdx.x;
#pragma unroll
    for (int j = 0; j < NBMAX / 256; ++j) cnt[tid + j * 256] = 0;
    __syncthreads();
    int e0 = blockIdx.x * EPB;
    for (int r = 0; r < EPB / 256; ++r) {
        int i = e0 + r * 256 + tid;
        if (i < E) atomicAdd(&cnt[dst[i] >> 6], 1);
    }
    __syncthreads();
    for (int j = 0; j < NBMAX / 256; ++j) {
        int b = tid + j * 256;
        if (b < NB) {
            int c = cnt[b];
            cnt[b] = (c > 0) ? atomicAdd(&gcur[b], c) : 0;
        }
    }
    __syncthreads();
    for (int r = 0; r < EPB / 256; ++r) {
        int i = e0 + r * 256 + tid;
        if (i < E) {
            int d = dst[i];
            int s = src[i];
            int bb = d >> 6;
            int p = atomicAdd(&cnt[bb], 1);
            if (p < CAP) binned[(size_t)bb * CAP + p] = ((u32)(d & 63) << 17) | (u32)s;
        }
    }
}

// ---------------- build pass 2: exclusive scan of bucket counts ----------------

__global__ __launch_bounds__(256) void bucket_scan_kernel(
        const int* __restrict__ gcur, int* __restrict__ bbase,
        int* __restrict__ rp, int N, int NB) {
    __shared__ int tsum[256];
    int tid = threadIdx.x;
    int loc[7];
    int run = 0;
#pragma unroll
    for (int j = 0; j < 7; ++j) {
        int b = tid * 7 + j;
        int v = 0;
        if (b < NB) { v = gcur[b]; if (v > CAP) v = CAP; }
        loc[j] = run;
        run += v;
    }
    tsum[tid] = run;
    __syncthreads();
    for (int off = 1; off < 256; off <<= 1) {
        int t = (tid >= off) ? tsum[tid - off] : 0;
        __syncthreads();
        tsum[tid] += t;
        __syncthreads();
    }
    int texcl = tsum[tid] - run;
#pragma unroll
    for (int j = 0; j < 7; ++j) {
        int b = tid * 7 + j;
        if (b < NB) bbase[b] = texcl + loc[j];
    }
    if (tid == 255) rp[N] = tsum[255];   // == E
}

// ---------------- build pass 3: per-bucket (dst, src-range) CSR in LDS ----------------
// key = local_dst*32 + (src>>12): counting sort -> per node, edges grouped into
// 32 ascending 4096-node src ranges (src-sorted csr). Emits rp, dinv.

__global__ __launch_bounds__(256) void buildcsr_kernel(
        const u32* __restrict__ binned, const int* __restrict__ gcur,
        const int* __restrict__ bbase, int* __restrict__ rp,
        float* __restrict__ dinv, int* __restrict__ csr, int N) {
    __shared__ u32 eb[CAP];        // 16 KB staged packed edges
    __shared__ int lcsr[CAP];      // 16 KB bucket-local csr
    __shared__ int cnt2[2048];     // 8 KB (local_dst*32 + srchi)
    __shared__ int cur2[2048];     // 8 KB cursors / scan
    __shared__ int tsum[256];
    int b = blockIdx.x;
    int tid = threadIdx.x;
    int cntB = gcur[b]; if (cntB > CAP) cntB = CAP;
    int base = bbase[b];
#pragma unroll
    for (int j = 0; j < 8; ++j) cnt2[tid * 8 + j] = 0;
    __syncthreads();
    for (int idx = tid; idx < cntB; idx += 256) {
        u32 v = binned[(size_t)b * CAP + idx];
        eb[idx] = v;
        int key = (int)(((v >> 17) << 5) | ((v & 0x1FFFFu) >> 12));
        atomicAdd(&cnt2[key], 1);
    }
    __syncthreads();
    // hierarchical exclusive scan of cnt2[0..2048)
    int loc[8];
    int run = 0;
#pragma unroll
    for (int j = 0; j < 8; ++j) { loc[j] = run; run += cnt2[tid * 8 + j]; }
    tsum[tid] = run;
    __syncthreads();
    for (int off = 1; off < 256; off <<= 1) {
        int t = (tid >= off) ? tsum[tid - off] : 0;
        __syncthreads();
        tsum[tid] += t;
        __syncthreads();
    }
    int texcl = tsum[tid] - run;
#pragma unroll
    for (int j = 0; j < 8; ++j) cur2[tid * 8 + j] = texcl + loc[j];
    __syncthreads();
    if (tid < 64) {
        int node = b * 64 + tid;
        int lo = cur2[tid * 32];
        int hi = (tid == 63) ? cntB : cur2[(tid + 1) * 32];
        if (node < N) {
            rp[node] = base + lo;
            dinv[node] = rsqrtf(1.0f + (float)(hi - lo));   // +1 self-loop
        }
    }
    __syncthreads();
    for (int idx = tid; idx < cntB; idx += 256) {
        u32 v = eb[idx];
        int key = (int)(((v >> 17) << 5) | ((v & 0x1FFFFu) >> 12));
        int p = atomicAdd(&cur2[key], 1);
        lcsr[p] = (int)(v & 0x1FFFFu);
    }
    __syncthreads();
    for (int idx = tid; idx < cntB; idx += 256)
        csr[base + idx] = lcsr[idx];   // fully coalesced
}

// ---------------- weight pre-pack to MFMA fragment order (bf16) ----------------

__global__ void prepw1_kernel(const float* __restrict__ W1, u16* __restrict__ W1f) {
    int f = blockIdx.x * 256 + threadIdx.x;   // 16384 frags
    int lane = f & 63;
    int nt = (f >> 6) & 3;
    int w  = (f >> 8) & 3;
    int t  = f >> 10;
    int col = w * 64 + nt * 16 + (lane & 15);
    int k0  = t * 32 + ((lane >> 4) << 3);
    u32 pk[4];
#pragma unroll
    for (int j = 0; j < 4; ++j) {
        u16 lo = f2bf(W1[(size_t)(k0 + 2 * j) * 256 + col]);
        u16 hi = f2bf(W1[(size_t)(k0 + 2 * j + 1) * 256 + col]);
        pk[j] = (u32)lo | ((u32)hi << 16);
    }
    *(uint4*)&W1f[(size_t)f * 8] = make_uint4(pk[0], pk[1], pk[2], pk[3]);
}

__global__ void prepw2_kernel(const float* __restrict__ W2, u16* __restrict__ W2f) {
    int f = blockIdx.x * 256 + threadIdx.x;   // 2048 frags
    int lane = f & 63;
    int nt = (f >> 6) & 3;
    int t  = f >> 8;
    int col = nt * 16 + (lane & 15);
    int k0  = t * 32 + ((lane >> 4) << 3);
    u32 pk[4];
#pragma unroll
    for (int j = 0; j < 4; ++j) {
        u16 lo = f2bf(W2[(size_t)(k0 + 2 * j) * 64 + col]);
        u16 hi = f2bf(W2[(size_t)(k0 + 2 * j + 1) * 64 + col]);
        pk[j] = (u32)lo | ((u32)hi << 16);
    }
    *(uint4*)&W2f[(size_t)f * 8] = make_uint4(pk[0], pk[1], pk[2], pk[3]);
}

// ---------------- fused MLP -> h0 (fp32) and hs = dinv*h0 (fp16) ----------------
// (R1-verified structure, 121us: x staged in LDS dbuf, B-frags global, h1s swizzled.)

__global__ __launch_bounds__(256) void mlp_kernel(
        const float* __restrict__ x, const u16* __restrict__ W1f,
        const float* __restrict__ b1, const u16* __restrict__ W2f,
        const float* __restrict__ b2, const float* __restrict__ dinv,
        float* __restrict__ h0, _Float16* __restrict__ hA, int N) {
    __shared__ char lds[32768];
    u16* xs  = (u16*)lds;              // phase1: [2][64][40] u16 dbuf (10240 B)
    u16* h1s = (u16*)lds;              // phase2: [64][256] u16 swizzled (32768 B)

    const int tid  = threadIdx.x;
    const int wave = tid >> 6;
    const int lane = tid & 63;
    const int lq   = lane >> 4;
    const int lr   = lane & 15;
    const int blockRow = blockIdx.x * 64;

    const int sr = tid >> 2;
    const int sc = (tid & 3) << 3;
    const int gr = blockRow + sr;
    const bool haveRow = (gr < N);
    const float* xp = x + (size_t)(haveRow ? gr : 0) * 512 + sc;

    f32x4 acc[4][4];
#pragma unroll
    for (int a = 0; a < 4; ++a)
#pragma unroll
        for (int b = 0; b < 4; ++b) acc[a][b] = (f32x4){0.f, 0.f, 0.f, 0.f};

    // prologue: stage x tile 0 into buf 0
    {
        float v[8];
#pragma unroll
        for (int j = 0; j < 8; ++j) v[j] = 0.f;
        if (haveRow) {
            float4 u0 = *(const float4*)(xp);
            float4 u1 = *(const float4*)(xp + 4);
            v[0]=u0.x; v[1]=u0.y; v[2]=u0.z; v[3]=u0.w;
            v[4]=u1.x; v[5]=u1.y; v[6]=u1.z; v[7]=u1.w;
        }
        u32 pk[4];
#pragma unroll
        for (int j = 0; j < 4; ++j)
            pk[j] = (u32)f2bf(v[2*j]) | ((u32)f2bf(v[2*j+1]) << 16);
        *(uint4*)&xs[sr * 40 + sc] = make_uint4(pk[0], pk[1], pk[2], pk[3]);
    }

    const bfx8* w1q = (const bfx8*)W1f;

    // ---- GEMM1: K=512 in 16 steps of 32 ----
    for (int t = 0; t < 16; ++t) {
        bfx8 fb0 = w1q[(t * 16 + wave * 4 + 0) * 64 + lane];
        bfx8 fb1 = w1q[(t * 16 + wave * 4 + 1) * 64 + lane];
        bfx8 fb2 = w1q[(t * 16 + wave * 4 + 2) * 64 + lane];
        bfx8 fb3 = w1q[(t * 16 + wave * 4 + 3) * 64 + lane];
        float v[8];
#pragma unroll
        for (int j = 0; j < 8; ++j) v[j] = 0.f;
        if (t < 15 && haveRow) {
            const float* p = xp + (t + 1) * 32;
            float4 u0 = *(const float4*)(p);
            float4 u1 = *(const float4*)(p + 4);
            v[0]=u0.x; v[1]=u0.y; v[2]=u0.z; v[3]=u0.w;
            v[4]=u1.x; v[5]=u1.y; v[6]=u1.z; v[7]=u1.w;
        }
        __syncthreads();
        const u16* cur = xs + (t & 1) * 2560;
        bfx8 fa[4];
#pragma unroll
        for (int mt = 0; mt < 4; ++mt)
            fa[mt] = *(const bfx8*)&cur[(mt * 16 + lr) * 40 + lq * 8];
#pragma unroll
        for (int mt = 0; mt < 4; ++mt) {
            acc[mt][0] = __builtin_amdgcn_mfma_f32_16x16x32_bf16(fa[mt], fb0, acc[mt][0], 0, 0, 0);
            acc[mt][1] = __builtin_amdgcn_mfma_f32_16x16x32_bf16(fa[mt], fb1, acc[mt][1], 0, 0, 0);
            acc[mt][2] = __builtin_amdgcn_mfma_f32_16x16x32_bf16(fa[mt], fb2, acc[mt][2], 0, 0, 0);
            acc[mt][3] = __builtin_amdgcn_mfma_f32_16x16x32_bf16(fa[mt], fb3, acc[mt][3], 0, 0, 0);
        }
        if (t < 15) {
            u16* nxt = xs + ((t + 1) & 1) * 2560;
            u32 pk[4];
#pragma unroll
            for (int j = 0; j < 4; ++j)
                pk[j] = (u32)f2bf(v[2*j]) | ((u32)f2bf(v[2*j+1]) << 16);
            *(uint4*)&nxt[sr * 40 + sc] = make_uint4(pk[0], pk[1], pk[2], pk[3]);
        }
    }
    __syncthreads();   // all fa reads done; reuse LDS as h1s

    // ---- epilogue1: bias+relu -> h1s (bf16, swizzled col ^= (row&7)<<3) ----
#pragma unroll
    for (int nt = 0; nt < 4; ++nt) {
        int col = wave * 64 + nt * 16 + lr;
        float bb = b1[col];
#pragma unroll
        for (int mt = 0; mt < 4; ++mt)
#pragma unroll
            for (int r = 0; r < 4; ++r) {
                int row = mt * 16 + lq * 4 + r;
                float vv = acc[mt][nt][r] + bb;
                vv = vv > 0.f ? vv : 0.f;
                h1s[row * 256 + (col ^ ((row & 7) << 3))] = f2bf(vv);
            }
    }
    __syncthreads();

    // ---- GEMM2: wave w -> rows [16w,16w+16), cols 0..63, K=256 ----
    f32x4 acc2[4];
#pragma unroll
    for (int a = 0; a < 4; ++a) acc2[a] = (f32x4){0.f, 0.f, 0.f, 0.f};
    const bfx8* w2q = (const bfx8*)W2f;
    const int row2 = wave * 16 + lr;
    const int sw2  = (row2 & 7) << 3;
#pragma unroll
    for (int t2 = 0; t2 < 8; ++t2) {
        bfx8 a = *(const bfx8*)&h1s[row2 * 256 + ((t2 * 32 + lq * 8) ^ sw2)];
#pragma unroll
        for (int nt = 0; nt < 4; ++nt) {
            bfx8 b = w2q[(t2 * 4 + nt) * 64 + lane];
            acc2[nt] = __builtin_amdgcn_mfma_f32_16x16x32_bf16(a, b, acc2[nt], 0, 0, 0);
        }
    }
    // ---- epilogue2: bias, store h0 (fp32) and hs=dinv*h0 (fp16) ----
#pragma unroll
    for (int nt = 0; nt < 4; ++nt) {
        int col = nt * 16 + lr;
        float bb = b2[col];
#pragma unroll
        for (int r = 0; r < 4; ++r) {
            int row = wave * 16 + lq * 4 + r;
            int g = blockRow + row;
            if (g < N) {
                float vv = acc2[nt][r] + bb;
                size_t idx = (size_t)g * 64 + col;
                h0[idx] = vv;
                hA[idx] = (_Float16)(vv * dinv[g]);
            }
        }
    }
}

// ---------------- propagation: 8 threads/node, 16B/lane, pure-sum gather ----------------
// csr is src-sorted per node -> all in-flight nodes at similar edge-index read a
// ~1-2MB src window: L2-resident for free.

template <typename OUTT>
__global__ __launch_bounds__(256) void prop_kernel(
        const _Float16* __restrict__ hs, const float* __restrict__ h0,
        const float* __restrict__ dinv, const int* __restrict__ rp,
        const int* __restrict__ csr, OUTT* __restrict__ hout, int N) {
    int t = blockIdx.x * 256 + threadIdx.x;
    int i = t >> 3;
    int l = t & 7;
    if (i >= N) return;
    int beg = rp[i], end = rp[i + 1];
    const _Float16* hb = hs + l * 8;
    h16x8 self = *(const h16x8*)(hb + (size_t)i * 64);
    float a[8];
#pragma unroll
    for (int j = 0; j < 8; ++j) a[j] = (float)self[j];   // self-loop folded into init
    int e = beg;
    for (; e + 3 < end; e += 4) {                        // 4x unroll
        int s0 = csr[e], s1 = csr[e + 1], s2 = csr[e + 2], s3 = csr[e + 3];
        h16x8 g0 = *(const h16x8*)(hb + (size_t)s0 * 64);
        h16x8 g1 = *(const h16x8*)(hb + (size_t)s1 * 64);
        h16x8 g2 = *(const h16x8*)(hb + (size_t)s2 * 64);
        h16x8 g3 = *(const h16x8*)(hb + (size_t)s3 * 64);
#pragma unroll
        for (int j = 0; j < 8; ++j) a[j] += (float)g0[j];
#pragma unroll
        for (int j = 0; j < 8; ++j) a[j] += (float)g1[j];
#pragma unroll
        for (int j = 0; j < 8; ++j) a[j] += (float)g2[j];
#pragma unroll
        for (int j = 0; j < 8; ++j) a[j] += (float)g3[j];
    }
    for (; e < end; ++e) {
        int s0 = csr[e];
        h16x8 g0 = *(const h16x8*)(hb + (size_t)s0 * 64);
#pragma unroll
        for (int j = 0; j < 8; ++j) a[j] += (float)g0[j];
    }
    float dv = dinv[i];
    float c1 = 0.9f * dv;
    const float* h0p = h0 + (size_t)i * 64 + l * 8;
    float o[8];
#pragma unroll
    for (int j = 0; j < 8; ++j) o[j] = fmaf(c1, a[j], 0.1f * h0p[j]);
    if constexpr (sizeof(OUTT) == 2) {
        h16x8 ov;
#pragma unroll
        for (int j = 0; j < 8; ++j) ov[j] = (_Float16)(dv * o[j]);   // store hs_new
        *(h16x8*)(hout + (size_t)i * 64 + l * 8) = ov;
    } else {
        float4* q = (float4*)(hout + (size_t)i * 64 + l * 8);
        q[0] = make_float4(o[0], o[1], o[2], o[3]);
        q[1] = make_float4(o[4], o[5], o[6], o[7]);
    }
}

// ---------------- launch ----------------

extern "C" void kernel_launch(void* const* d_in, const int* in_sizes, int n_in,
                              void* d_out, int out_size, void* d_ws, size_t ws_size,
                              hipStream_t stream) {
    const float* x  = (const float*)d_in[0];
    const int*   ei = (const int*)d_in[1];
    const float* W1 = (const float*)d_in[2];
    const float* b1 = (const float*)d_in[3];
    const float* W2 = (const float*)d_in[4];
    const float* b2 = (const float*)d_in[5];
    const int N = in_sizes[0] / 512;
    const int E = in_sizes[1] / 2;
    const int NB = (N + 63) / 64;
    const int* src = ei;
    const int* dst = ei + E;

    char* w = (char*)d_ws;
    size_t off = 0;
    auto alloc = [&](size_t bytes) -> char* {
        char* p = w + off;
        off = (off + bytes + 1023) & ~(size_t)1023;
        return p;
    };
    int*      gcur  = (int*)alloc((size_t)NB * 4);
    int*      bbase = (int*)alloc((size_t)NB * 4);
    int*      rp    = (int*)alloc(((size_t)N + 1) * 4);
    float*    dinv  = (float*)alloc((size_t)N * 4);
    int*      csr   = (int*)alloc((size_t)E * 4);
    u32*      binned= (u32*)alloc((size_t)NB * CAP * 4);
    u16*      W1f   = (u16*)alloc(512 * 256 * 2);
    u16*      W2f   = (u16*)alloc(256 * 64 * 2);
    float*    h0    = (float*)alloc((size_t)N * 64 * 4);
    _Float16* hA    = (_Float16*)alloc((size_t)N * 64 * 2);
    _Float16* hB    = (_Float16*)alloc((size_t)N * 64 * 2);
    // ws use ~91 MB

    hipMemsetAsync(gcur, 0, (size_t)NB * 4, stream);
    binscat_kernel<<<(E + EPB - 1) / EPB, 256, 0, stream>>>(src, dst, gcur, binned, E, NB);
    bucket_scan_kernel<<<1, 256, 0, stream>>>(gcur, bbase, rp, N, NB);
    buildcsr_kernel<<<NB, 256, 0, stream>>>(binned, gcur, bbase, rp, dinv, csr, N);
    prepw1_kernel<<<64, 256, 0, stream>>>(W1, W1f);
    prepw2_kernel<<<8, 256, 0, stream>>>(W2, W2f);
    mlp_kernel<<<(N + 63) / 64, 256, 0, stream>>>(x, W1f, b1, W2f, b2, dinv, h0, hA, N);

    const _Float16* pin = hA;
    int grid = (N * 8 + 255) / 256;
    for (int it = 0; it < 9; ++it) {
        _Float16* pout = (it & 1) ? hA : hB;
        prop_kernel<_Float16><<<grid, 256, 0, stream>>>(pin, h0, dinv, rp, csr, pout, N);
        pin = pout;
    }
    prop_kernel<float><<<grid, 256, 0, stream>>>(pin, h0, dinv, rp, csr, (float*)d_out, N);
}